// Round 1
// baseline (37081.738 us; speedup 1.0000x reference)
//
#include <hip/hip_runtime.h>
#include <climits>

#define NPTS 65536
#define NB 32
#define NS 2048
#define NSAMP (NB * NS)
#define EPSBN 1e-5f
#define C1 64
#define C2 128
#define C3 256

#define FPS_T 512
#define PPT (NPTS / FPS_T)  // 128 points per thread

// workspace float offsets
#define SUM0 0
#define SQ0 64
#define SUM1 128
#define SQ1 256
#define SUM2 384
#define SQ2 640
#define A0O 896
#define T0O 960
#define A1O 1024
#define T1O 1152
#define A2O 1280
#define T2O 1536
#define ACC_ZERO_BYTES (896 * 4)

// ---------------------------------------------------------------------------
// FPS: one workgroup (512 threads) per batch. dist[] lives in VGPRs.
// Distance computed in exact NumPy order (no FMA contraction) so the argmax
// sequence matches the reference bit-for-bit; ties broken to lowest index.
// ---------------------------------------------------------------------------
__global__ __launch_bounds__(FPS_T, 2) void fps_kernel(const float* __restrict__ xyz,
                                                       float* __restrict__ out_xyz) {
  const int b = blockIdx.x;
  const int tid = threadIdx.x;
  const float* __restrict__ P = xyz + (size_t)b * NPTS * 3;
  __shared__ float cs[3];
  __shared__ float wmax[FPS_T / 64];
  __shared__ int nbest[2];

  float dist[PPT];
#pragma unroll
  for (int i = 0; i < PPT; ++i) dist[i] = 1e10f;

  if (tid == 0) {
    cs[0] = P[0]; cs[1] = P[1]; cs[2] = P[2];
    nbest[0] = INT_MAX; nbest[1] = INT_MAX;
  }
  __syncthreads();

  for (int k = 0; k < NS; ++k) {
    const float cx = cs[0], cy = cs[1], cz = cs[2];
    if (tid == 0) {  // emit far_k (pre-update), matching the scan's output order
      float* o = out_xyz + ((size_t)b * NS + k) * 3;
      o[0] = cx; o[1] = cy; o[2] = cz;
    }
    float lm0 = -1.f, lm1 = -1.f, lm2 = -1.f, lm3 = -1.f;
#pragma unroll
    for (int i = 0; i < PPT; ++i) {
      const float* q = P + (size_t)(i * FPS_T + tid) * 3;
      const float dx = q[0] - cx;
      const float dy = q[1] - cy;
      const float dz = q[2] - cz;
      // exact ((dx*dx + dy*dy) + dz*dz), no fma contraction
      const float d = __fadd_rn(__fadd_rn(__fmul_rn(dx, dx), __fmul_rn(dy, dy)),
                                __fmul_rn(dz, dz));
      const float nd = fminf(dist[i], d);
      dist[i] = nd;
      if ((i & 3) == 0) lm0 = fmaxf(lm0, nd);
      else if ((i & 3) == 1) lm1 = fmaxf(lm1, nd);
      else if ((i & 3) == 2) lm2 = fmaxf(lm2, nd);
      else lm3 = fmaxf(lm3, nd);
    }
    float wm = fmaxf(fmaxf(lm0, lm1), fmaxf(lm2, lm3));
#pragma unroll
    for (int off = 32; off > 0; off >>= 1) wm = fmaxf(wm, __shfl_xor(wm, off, 64));
    if ((tid & 63) == 0) wmax[tid >> 6] = wm;
    const int p = k & 1;
    __syncthreads();
    float gmax = wmax[0];
#pragma unroll
    for (int w = 1; w < FPS_T / 64; ++w) gmax = fmaxf(gmax, wmax[w]);
    if (tid == 0) nbest[p ^ 1] = INT_MAX;  // reset other buffer for next iter
    if (wm == gmax) {  // only wave(s) holding the global max scan
      int myb = INT_MAX;
#pragma unroll
      for (int i = 0; i < PPT; ++i)
        if (dist[i] == gmax) myb = min(myb, i * FPS_T + tid);
      if (myb != INT_MAX) atomicMin(&nbest[p], myb);
    }
    __syncthreads();
    const int nstar = nbest[p];
    if (tid == (nstar & (FPS_T - 1))) {
      const float* q = P + (size_t)nstar * 3;
      cs[0] = q[0]; cs[1] = q[1]; cs[2] = q[2];
    }
    __syncthreads();
  }
}

// ---------------------------------------------------------------------------
// MLP (recompute strategy; workspace only holds per-channel stats ~8 KB)
// ---------------------------------------------------------------------------
__device__ __forceinline__ float wredsum(float v) {
#pragma unroll
  for (int off = 32; off > 0; off >>= 1) v += __shfl_xor(v, off, 64);
  return v;
}
__device__ __forceinline__ float wredmax(float v) {
#pragma unroll
  for (int off = 32; off > 0; off >>= 1) v = fmaxf(v, __shfl_xor(v, off, 64));
  return v;
}

__global__ __launch_bounds__(256) void pass1_kernel(const float* __restrict__ sx,
                                                    const float* __restrict__ w0,
                                                    const float* __restrict__ b0,
                                                    float* __restrict__ acc) {
  const int sg = blockIdx.x * 256 + threadIdx.x;
  const int lane = threadIdx.x & 63;
  const float x0 = sx[(size_t)sg * 3 + 0];
  const float x1 = sx[(size_t)sg * 3 + 1];
  const float x2 = sx[(size_t)sg * 3 + 2];
  float aS = 0.f, aQ = 0.f;
#pragma unroll
  for (int o = 0; o < C1; ++o) {
    const float v = b0[o] + w0[o * 3 + 0] * x0 + w0[o * 3 + 1] * x1 + w0[o * 3 + 2] * x2;
    const float s = wredsum(v);
    const float q = wredsum(v * v);
    if (lane == o) { aS = s; aQ = q; }
  }
  atomicAdd(&acc[SUM0 + lane], aS);
  atomicAdd(&acc[SQ0 + lane], aQ);
}

__global__ void fin_kernel(const float* __restrict__ s, const float* __restrict__ q,
                           const float* __restrict__ g, const float* __restrict__ be,
                           float* __restrict__ a, float* __restrict__ t, int C) {
  const int c = threadIdx.x;
  if (c < C) {
    const float mean = s[c] * (1.0f / NSAMP);
    const float var = q[c] * (1.0f / NSAMP) - mean * mean;
    const float ai = g[c] / sqrtf(var + EPSBN);
    a[c] = ai;
    t[c] = be[c] - mean * ai;
  }
}

__global__ __launch_bounds__(256) void pass2_kernel(const float* __restrict__ sx,
    const float* __restrict__ w0, const float* __restrict__ b0,
    const float* __restrict__ a0, const float* __restrict__ t0,
    const float* __restrict__ w1, const float* __restrict__ b1,
    float* __restrict__ acc) {
  const int sg = blockIdx.x * 256 + threadIdx.x;
  const int lane = threadIdx.x & 63;
  const float x0 = sx[(size_t)sg * 3 + 0];
  const float x1 = sx[(size_t)sg * 3 + 1];
  const float x2 = sx[(size_t)sg * 3 + 2];
  float h[C1];
#pragma unroll
  for (int o = 0; o < C1; ++o) {
    const float v = b0[o] + w0[o * 3 + 0] * x0 + w0[o * 3 + 1] * x1 + w0[o * 3 + 2] * x2;
    h[o] = fmaxf(a0[o] * v + t0[o], 0.f);
  }
  float aS[2] = {0.f, 0.f}, aQ[2] = {0.f, 0.f};
#pragma unroll
  for (int j = 0; j < 2; ++j) {
    for (int oo = 0; oo < 64; ++oo) {
      const int o = j * 64 + oo;
      float v0 = b1[o], v1 = 0.f, v2 = 0.f, v3 = 0.f;
#pragma unroll
      for (int c = 0; c < C1; c += 4) {
        v0 += w1[o * C1 + c + 0] * h[c + 0];
        v1 += w1[o * C1 + c + 1] * h[c + 1];
        v2 += w1[o * C1 + c + 2] * h[c + 2];
        v3 += w1[o * C1 + c + 3] * h[c + 3];
      }
      const float v = (v0 + v1) + (v2 + v3);
      const float sS = wredsum(v);
      const float sQ = wredsum(v * v);
      if (lane == oo) { aS[j] = sS; aQ[j] = sQ; }
    }
  }
#pragma unroll
  for (int j = 0; j < 2; ++j) {
    atomicAdd(&acc[SUM1 + j * 64 + lane], aS[j]);
    atomicAdd(&acc[SQ1 + j * 64 + lane], aQ[j]);
  }
}

__global__ __launch_bounds__(256, 2) void pass3_kernel(const float* __restrict__ sx,
    const float* __restrict__ w0, const float* __restrict__ b0,
    const float* __restrict__ a0, const float* __restrict__ t0,
    const float* __restrict__ w1, const float* __restrict__ b1,
    const float* __restrict__ a1, const float* __restrict__ t1,
    const float* __restrict__ w2, const float* __restrict__ b2,
    float* __restrict__ acc) {
  const int sg = blockIdx.x * 256 + threadIdx.x;
  const int lane = threadIdx.x & 63;
  const float x0 = sx[(size_t)sg * 3 + 0];
  const float x1 = sx[(size_t)sg * 3 + 1];
  const float x2 = sx[(size_t)sg * 3 + 2];
  float h[C1];
#pragma unroll
  for (int o = 0; o < C1; ++o) {
    const float v = b0[o] + w0[o * 3 + 0] * x0 + w0[o * 3 + 1] * x1 + w0[o * 3 + 2] * x2;
    h[o] = fmaxf(a0[o] * v + t0[o], 0.f);
  }
  float f[C2];
#pragma unroll
  for (int o = 0; o < C2; ++o) {
    float v0 = b1[o], v1 = 0.f, v2 = 0.f, v3 = 0.f;
#pragma unroll
    for (int c = 0; c < C1; c += 4) {
      v0 += w1[o * C1 + c + 0] * h[c + 0];
      v1 += w1[o * C1 + c + 1] * h[c + 1];
      v2 += w1[o * C1 + c + 2] * h[c + 2];
      v3 += w1[o * C1 + c + 3] * h[c + 3];
    }
    const float v = (v0 + v1) + (v2 + v3);
    f[o] = fmaxf(a1[o] * v + t1[o], 0.f);
  }
  float aS[4] = {0, 0, 0, 0}, aQ[4] = {0, 0, 0, 0};
#pragma unroll
  for (int j = 0; j < 4; ++j) {
    for (int oo = 0; oo < 64; ++oo) {
      const int o = j * 64 + oo;
      float v0 = b2[o], v1 = 0.f, v2 = 0.f, v3 = 0.f;
#pragma unroll
      for (int c = 0; c < C2; c += 4) {
        v0 += w2[o * C2 + c + 0] * f[c + 0];
        v1 += w2[o * C2 + c + 1] * f[c + 1];
        v2 += w2[o * C2 + c + 2] * f[c + 2];
        v3 += w2[o * C2 + c + 3] * f[c + 3];
      }
      const float v = (v0 + v1) + (v2 + v3);
      const float sS = wredsum(v);
      const float sQ = wredsum(v * v);
      if (lane == oo) { aS[j] = sS; aQ[j] = sQ; }
    }
  }
#pragma unroll
  for (int j = 0; j < 4; ++j) {
    atomicAdd(&acc[SUM2 + j * 64 + lane], aS[j]);
    atomicAdd(&acc[SQ2 + j * 64 + lane], aQ[j]);
  }
}

__global__ __launch_bounds__(256, 2) void pass4_kernel(const float* __restrict__ sx,
    const float* __restrict__ w0, const float* __restrict__ b0,
    const float* __restrict__ a0, const float* __restrict__ t0,
    const float* __restrict__ w1, const float* __restrict__ b1,
    const float* __restrict__ a1, const float* __restrict__ t1,
    const float* __restrict__ w2, const float* __restrict__ b2,
    const float* __restrict__ a2, const float* __restrict__ t2,
    float* __restrict__ feat) {
  const int sg = blockIdx.x * 256 + threadIdx.x;
  const int lane = threadIdx.x & 63;
  const float x0 = sx[(size_t)sg * 3 + 0];
  const float x1 = sx[(size_t)sg * 3 + 1];
  const float x2 = sx[(size_t)sg * 3 + 2];
  float h[C1];
#pragma unroll
  for (int o = 0; o < C1; ++o) {
    const float v = b0[o] + w0[o * 3 + 0] * x0 + w0[o * 3 + 1] * x1 + w0[o * 3 + 2] * x2;
    h[o] = fmaxf(a0[o] * v + t0[o], 0.f);
  }
  float f[C2];
#pragma unroll
  for (int o = 0; o < C2; ++o) {
    float v0 = b1[o], v1 = 0.f, v2 = 0.f, v3 = 0.f;
#pragma unroll
    for (int c = 0; c < C1; c += 4) {
      v0 += w1[o * C1 + c + 0] * h[c + 0];
      v1 += w1[o * C1 + c + 1] * h[c + 1];
      v2 += w1[o * C1 + c + 2] * h[c + 2];
      v3 += w1[o * C1 + c + 3] * h[c + 3];
    }
    const float v = (v0 + v1) + (v2 + v3);
    f[o] = fmaxf(a1[o] * v + t1[o], 0.f);
  }
  float fm[4] = {0, 0, 0, 0};
#pragma unroll
  for (int j = 0; j < 4; ++j) {
    for (int oo = 0; oo < 64; ++oo) {
      const int o = j * 64 + oo;
      float v0 = b2[o], v1 = 0.f, v2 = 0.f, v3 = 0.f;
#pragma unroll
      for (int c = 0; c < C2; c += 4) {
        v0 += w2[o * C2 + c + 0] * f[c + 0];
        v1 += w2[o * C2 + c + 1] * f[c + 1];
        v2 += w2[o * C2 + c + 2] * f[c + 2];
        v3 += w2[o * C2 + c + 3] * f[c + 3];
      }
      const float v = (v0 + v1) + (v2 + v3);
      const float z = fmaxf(a2[o] * v + t2[o], 0.f);  // relu >= 0
      const float m = wredmax(z);
      if (lane == oo) fm[j] = m;
    }
  }
  const int b = sg >> 11;  // 2048 samples per batch; waves never straddle b
  unsigned* fb = (unsigned*)feat + (size_t)b * C3;
#pragma unroll
  for (int j = 0; j < 4; ++j)
    atomicMax(&fb[j * 64 + lane], __float_as_uint(fm[j]));
}

// ---------------------------------------------------------------------------
extern "C" void kernel_launch(void* const* d_in, const int* in_sizes, int n_in,
                              void* d_out, int out_size, void* d_ws, size_t ws_size,
                              hipStream_t stream) {
  const float* xyz = (const float*)d_in[0];
  const float* w0 = (const float*)d_in[1];
  const float* b0 = (const float*)d_in[2];
  const float* g0 = (const float*)d_in[3];
  const float* be0 = (const float*)d_in[4];
  const float* w1 = (const float*)d_in[5];
  const float* b1 = (const float*)d_in[6];
  const float* g1 = (const float*)d_in[7];
  const float* be1 = (const float*)d_in[8];
  const float* w2 = (const float*)d_in[9];
  const float* b2 = (const float*)d_in[10];
  const float* g2 = (const float*)d_in[11];
  const float* be2 = (const float*)d_in[12];

  float* out = (float*)d_out;
  float* nx = out;                          // new_xyz [32][2048][3]
  float* feat = out + (size_t)NB * NS * 3;  // features [32][256]
  float* acc = (float*)d_ws;

  hipMemsetAsync(acc, 0, ACC_ZERO_BYTES, stream);
  hipMemsetAsync(feat, 0, (size_t)NB * C3 * 4, stream);

  fps_kernel<<<NB, FPS_T, 0, stream>>>(xyz, nx);

  const int nblk = NSAMP / 256;
  pass1_kernel<<<nblk, 256, 0, stream>>>(nx, w0, b0, acc);
  fin_kernel<<<1, C1, 0, stream>>>(acc + SUM0, acc + SQ0, g0, be0, acc + A0O, acc + T0O, C1);
  pass2_kernel<<<nblk, 256, 0, stream>>>(nx, w0, b0, acc + A0O, acc + T0O, w1, b1, acc);
  fin_kernel<<<1, C2, 0, stream>>>(acc + SUM1, acc + SQ1, g1, be1, acc + A1O, acc + T1O, C2);
  pass3_kernel<<<nblk, 256, 0, stream>>>(nx, w0, b0, acc + A0O, acc + T0O, w1, b1,
                                         acc + A1O, acc + T1O, w2, b2, acc);
  fin_kernel<<<1, C3, 0, stream>>>(acc + SUM2, acc + SQ2, g2, be2, acc + A2O, acc + T2O, C3);
  pass4_kernel<<<nblk, 256, 0, stream>>>(nx, w0, b0, acc + A0O, acc + T0O, w1, b1,
                                         acc + A1O, acc + T1O, w2, b2,
                                         acc + A2O, acc + T2O, feat);
}